// Round 7
// baseline (158.249 us; speedup 1.0000x reference)
//
#include <hip/hip_runtime.h>

#define DIMK 64
#define MC 256
#define BR 64                    // rows per tile
#define NROWS 262144
#define NT (NROWS / BR)          // 4096 tiles
#define PBLK 512                 // persistent blocks (2 per CU)
#define TPB (NT / PBLK)          // 8 tiles per block

// workspace layout (bytes):
//   [0, 1024)            cvec fp32 (256 floats)            [always]
//   [1024, 1024+65536)   At fp16 hi/lo image (fast path only, ws_size-guarded):
//     plane-major: hi-half at WS_AT + ((s*4 + kc)*256 + col)*16, kc = 2*ksl + hi
//     lo-half at +32768; j-th half of a chunk is k = s*32 + kc*8 + j
#define WS_AT 1024
#define WS_NEED (1024 + 65536)

// fast-path LDS: At image [0,65536) + parity-dbuf gm [65536, 65536+2048)
#define LDS_GMP 65536
#define LDS_FP_SIZE (65536 + 2048)

// fallback-path LDS offsets (round-3 proven layout)
#define LDS_AH 0
#define LDS_AL 16384
#define LDS_GM 32768

typedef _Float16 half8 __attribute__((ext_vector_type(8)));
typedef float f32x16 __attribute__((ext_vector_type(16)));

__device__ __forceinline__ void cvt_half8(const float* v, half8& h, half8& l) {
#pragma unroll
    for (int j = 0; j < 8; ++j) {
        h[j] = (_Float16)v[j];
        l[j] = (_Float16)(v[j] - (float)h[j]);
    }
}

// cvec only (1 KB ws — proven-safe footprint)
__global__ void precompute_c(const float* __restrict__ pivot,
                             const float* __restrict__ At,
                             float* __restrict__ ws) {
    const int t = threadIdx.x;
    float acc = 0.f;
#pragma unroll
    for (int k = 0; k < DIMK; ++k) acc = fmaf(pivot[k], At[k * MC + t], acc);
    ws[t] = acc;
}

// cvec + one-time At -> fp16 hi/lo split, plane-major image (fast path)
__global__ void precompute_at(const float* __restrict__ pivot,
                              const float* __restrict__ At,
                              float* __restrict__ ws) {
    const int t = threadIdx.x;              // column 0..255
    float col[DIMK];
    float acc = 0.f;
#pragma unroll
    for (int k = 0; k < DIMK; ++k) {
        col[k] = At[k * MC + t];            // coalesced across t
        acc = fmaf(pivot[k], col[k], acc);
    }
    ws[t] = acc;                            // cvec, fp32
    char* wsb = (char*)ws + WS_AT;
#pragma unroll
    for (int s = 0; s < 2; ++s) {
#pragma unroll
        for (int kc = 0; kc < 4; ++kc) {
            half8 h, l;
#pragma unroll
            for (int j = 0; j < 8; ++j) {
                const float v = col[s * 32 + kc * 8 + j];
                h[j] = (_Float16)v;
                l[j] = (_Float16)(v - (float)h[j]);
            }
            const int off = ((s * 4 + kc) * 256 + t) * 16;
            *(half8*)(wsb + off) = h;
            *(half8*)(wsb + off + 32768) = l;
        }
    }
}

// ===================== fast path: persistent, 512 thr, 4 waves/SIMD ==========
__global__ __launch_bounds__(512, 4)
void fused_constrain_p(const float* __restrict__ z,
                       const float* __restrict__ pivot,
                       const float* __restrict__ b,
                       const float* __restrict__ ws,
                       float* __restrict__ out) {
    extern __shared__ __align__(16) char lds[];

    const int tid  = threadIdx.x;
    const int lane = tid & 63;
    const int li   = lane & 31;      // B col lane / A row lane
    const int hi   = lane >> 5;      // k-octet selector
    const int wid  = tid >> 6;       // 0..7
    const int rg   = wid >> 2;       // row group: rows rg*32..+32
    const int cg   = wid & 3;        // col group: cols cg*64..+64
    const int R0   = rg * 32;
    const int colbase = cg * 64;

    // loop-invariant constants
    float bv[2], cv[2];
#pragma unroll
    for (int ct = 0; ct < 2; ++ct) {
        const int c = colbase + ct * 32 + li;
        bv[ct] = b[c];
        cv[ct] = ws[c];              // cvec fp32
    }
    const float2 p2 = *(const float2*)(pivot + 2 * li);

    // issue tile-0 k-half-0 z prefetch (hidden under At staging)
    float4 zfA[4];
    {
        const float* zr = z + blockIdx.x * (TPB * BR * DIMK) +
                          (R0 + li) * DIMK + hi * 8;
        zfA[0] = *(const float4*)(zr);
        zfA[1] = *(const float4*)(zr + 4);
        zfA[2] = *(const float4*)(zr + 16);
        zfA[3] = *(const float4*)(zr + 20);
    }

    // stage the full 64 KB At image into LDS ONCE (512 thr x 16B x 8)
    {
        const char* wsA = (const char*)ws + WS_AT;
#pragma unroll
        for (int p = 0; p < 8; ++p) {
            const int f = p * 512 + tid;
            *(float4*)(lds + f * 16) = *(const float4*)(wsA + f * 16);
        }
    }
    __syncthreads();

    const int Bbase = hi * 4096 + (colbase + li) * 16;

    // per-tile body; zc = this tile's k-half-0 regs, zn = next tile's target
    auto tile_body = [&](float4 (&zc)[4], float4 (&zn)[4],
                         const int i, const bool pf) {
        const int tbase = (blockIdx.x * TPB + i) * (BR * DIMK);
        const float* zr = z + tbase + (R0 + li) * DIMK + hi * 8;

        // current tile k-half-1 loads (needed after convert+MFMA of half 0)
        float4 zs1[4];
        zs1[0] = *(const float4*)(zr + 32);
        zs1[1] = *(const float4*)(zr + 36);
        zs1[2] = *(const float4*)(zr + 48);
        zs1[3] = *(const float4*)(zr + 52);
        // next tile k-half-0 prefetch (consumed next call)
        if (pf) {
            const float* zp = zr + BR * DIMK;
            zn[0] = *(const float4*)(zp);
            zn[1] = *(const float4*)(zp + 4);
            zn[2] = *(const float4*)(zp + 16);
            zn[3] = *(const float4*)(zp + 20);
        }

        f32x16 acc[2];
#pragma unroll
        for (int ct = 0; ct < 2; ++ct)
#pragma unroll
            for (int e = 0; e < 16; ++e) acc[ct][e] = 0.f;

        half8 azh[2], azl[2];

        auto mfma_step = [&](const int sOff) {
#pragma unroll
            for (int ksl = 0; ksl < 2; ++ksl) {
                const int ob = Bbase + sOff + ksl * 8192;
                const half8 ah = azh[ksl], al = azl[ksl];
#pragma unroll
                for (int ct = 0; ct < 2; ++ct) {
                    const half8 bh = *(const half8*)(lds + ob + ct * 512);
                    const half8 bl = *(const half8*)(lds + ob + ct * 512 + 32768);
                    acc[ct] = __builtin_amdgcn_mfma_f32_32x32x16_f16(ah, bh, acc[ct], 0, 0, 0);
                    acc[ct] = __builtin_amdgcn_mfma_f32_32x32x16_f16(ah, bl, acc[ct], 0, 0, 0);
                    acc[ct] = __builtin_amdgcn_mfma_f32_32x32x16_f16(al, bh, acc[ct], 0, 0, 0);
                }
            }
        };

        // ---- k-half 0: S += zh@ah + zh@al + zl@ah ----
        cvt_half8((const float*)zc, azh[0], azl[0]);
        cvt_half8((const float*)zc + 8, azh[1], azl[1]);
        mfma_step(0);
        // ---- k-half 1 ----
        cvt_half8((const float*)zs1, azh[0], azl[0]);
        cvt_half8((const float*)zs1 + 8, azh[1], azl[1]);
        mfma_step(16384);

        // ---- epilogue: masked alpha, col-max over wave's 64 cols ----
        float gm[16];
#pragma unroll
        for (int r = 0; r < 16; ++r) gm[r] = 0.f;
#pragma unroll
        for (int ct = 0; ct < 2; ++ct)
#pragma unroll
            for (int r = 0; r < 16; ++r) {
                const float sv = acc[ct][r];
                const float sa = sv - bv[ct];
                const float qd = fmaxf(sv - cv[ct], 1e-9f);
                // sa<0 gives negative alpha, excluded by fmax against gm>=0
                gm[r] = fmaxf(gm[r], sa * __builtin_amdgcn_rcpf(qd));
            }
#pragma unroll
        for (int r = 0; r < 16; ++r)
#pragma unroll
            for (int off = 1; off < 32; off <<= 1)
                gm[r] = fmaxf(gm[r], __shfl_xor(gm[r], off));

        // cross-wave combine over 4 cg groups (parity double-buffered)
        float* gmb = (float*)(lds + LDS_GMP + ((i & 1) << 10));
#pragma unroll
        for (int r = 0; r < 16; ++r) {
            const int row = (r & 3) + 8 * (r >> 2) + 4 * hi;   // C/D row map
            if (li == 0) gmb[((rg << 5) + row) * 4 + cg] = gm[r];
        }
        __syncthreads();   // only barrier per tile

        // each cg wave stores 4 r's (x2 hi) = 8 rows of its rg group
#pragma unroll
        for (int rr = 0; rr < 4; ++rr) {
            const int r   = cg * 4 + rr;
            const int row = (r & 3) + 8 * (r >> 2) + 4 * hi;
            const float* g4 = &gmb[((rg << 5) + row) * 4];
            const float g = fmaxf(fmaxf(g4[0], g4[1]), fmaxf(g4[2], g4[3]));
            const int idx = tbase + (R0 + row) * DIMK + 2 * li;
            const float2 zz = *(const float2*)(z + idx);  // L1/L2-hot exact z
            float2 o;
            o.x = fmaf(g, p2.x - zz.x, zz.x);
            o.y = fmaf(g, p2.y - zz.y, zz.y);
            *(float2*)(out + idx) = o;
        }
    };

    float4 zfB[4];
#pragma clang loop unroll(disable)
    for (int j = 0; j < TPB / 2; ++j) {
        tile_body(zfA, zfB, 2 * j, true);
        tile_body(zfB, zfA, 2 * j + 1, j < TPB / 2 - 1);
    }
}

// ===================== fallback: round-3 proven path ========================
__global__ __launch_bounds__(256, 4)
void fused_constrain_fb(const float* __restrict__ z,
                        const float* __restrict__ pivot,
                        const float* __restrict__ At,
                        const float* __restrict__ b,
                        const float* __restrict__ ws,
                        float* __restrict__ out) {
    __shared__ __align__(16) char lds[33280];

    const int tid  = threadIdx.x;
    const int lane = tid & 63;
    const int li   = lane & 31;
    const int hi   = lane >> 5;
    const int wid  = tid >> 6;
    const int rg   = wid >> 1;
    const int cg   = wid & 1;
    const int R0   = rg * 32;
    const int colbase = cg * 128;
    const int base = blockIdx.x * (BR * DIMK);

    float4 zf[8];
    {
        const float* zr = z + base + (R0 + li) * DIMK + hi * 8;
#pragma unroll
        for (int q = 0; q < 4; ++q) {
            const float* p = zr + (q >> 1) * 32 + (q & 1) * 16;
            zf[q * 2 + 0] = *(const float4*)(p);
            zf[q * 2 + 1] = *(const float4*)(p + 4);
        }
    }
    const int swzT = (tid & 3) ^ ((tid >> 2) & 3);
#pragma unroll
    for (int kc = 0; kc < 4; ++kc) {
        float v[8];
#pragma unroll
        for (int j = 0; j < 8; ++j) v[j] = At[(kc * 8 + j) * MC + tid];
        half8 h, l;
#pragma unroll
        for (int j = 0; j < 8; ++j) {
            h[j] = (_Float16)v[j];
            l[j] = (_Float16)(v[j] - (float)h[j]);
        }
        const int off = tid * 64 + ((kc ^ swzT) << 4);
        *(half8*)(lds + LDS_AH + off) = h;
        *(half8*)(lds + LDS_AL + off) = l;
    }

    half8 azh[4], azl[4];
    const float* zv = (const float*)zf;
#pragma unroll
    for (int q = 0; q < 4; ++q)
        cvt_half8(zv + q * 8, azh[q], azl[q]);

    f32x16 acc[4];
#pragma unroll
    for (int ct = 0; ct < 4; ++ct)
#pragma unroll
        for (int e = 0; e < 16; ++e) acc[ct][e] = 0.f;

    const int swz = (li & 3) ^ ((li >> 2) & 3);
    __syncthreads();
#pragma unroll
    for (int ksl = 0; ksl < 2; ++ksl) {
        const int cb = ((ksl * 2 + hi) ^ swz) << 4;
        const half8 ah = azh[ksl], al = azl[ksl];
#pragma unroll
        for (int ct = 0; ct < 4; ++ct) {
            const int off = (colbase + ct * 32 + li) * 64 + cb;
            const half8 bh = *(const half8*)(lds + LDS_AH + off);
            const half8 bl = *(const half8*)(lds + LDS_AL + off);
            acc[ct] = __builtin_amdgcn_mfma_f32_32x32x16_f16(ah, bh, acc[ct], 0, 0, 0);
            acc[ct] = __builtin_amdgcn_mfma_f32_32x32x16_f16(ah, bl, acc[ct], 0, 0, 0);
            acc[ct] = __builtin_amdgcn_mfma_f32_32x32x16_f16(al, bh, acc[ct], 0, 0, 0);
        }
    }
    __syncthreads();
#pragma unroll
    for (int kc = 0; kc < 4; ++kc) {
        float v[8];
#pragma unroll
        for (int j = 0; j < 8; ++j) v[j] = At[(32 + kc * 8 + j) * MC + tid];
        half8 h, l;
#pragma unroll
        for (int j = 0; j < 8; ++j) {
            h[j] = (_Float16)v[j];
            l[j] = (_Float16)(v[j] - (float)h[j]);
        }
        const int off = tid * 64 + ((kc ^ swzT) << 4);
        *(half8*)(lds + LDS_AH + off) = h;
        *(half8*)(lds + LDS_AL + off) = l;
    }
    __syncthreads();
#pragma unroll
    for (int ksl = 0; ksl < 2; ++ksl) {
        const int cb = ((ksl * 2 + hi) ^ swz) << 4;
        const half8 ah = azh[2 + ksl], al = azl[2 + ksl];
#pragma unroll
        for (int ct = 0; ct < 4; ++ct) {
            const int off = (colbase + ct * 32 + li) * 64 + cb;
            const half8 bh = *(const half8*)(lds + LDS_AH + off);
            const half8 bl = *(const half8*)(lds + LDS_AL + off);
            acc[ct] = __builtin_amdgcn_mfma_f32_32x32x16_f16(ah, bh, acc[ct], 0, 0, 0);
            acc[ct] = __builtin_amdgcn_mfma_f32_32x32x16_f16(ah, bl, acc[ct], 0, 0, 0);
            acc[ct] = __builtin_amdgcn_mfma_f32_32x32x16_f16(al, bh, acc[ct], 0, 0, 0);
        }
    }

    float bv[4], cv[4];
#pragma unroll
    for (int ct = 0; ct < 4; ++ct) {
        const int c = colbase + ct * 32 + li;
        bv[ct] = b[c];
        cv[ct] = ws[c];
    }
    float gm[16];
#pragma unroll
    for (int r = 0; r < 16; ++r) gm[r] = 0.f;
#pragma unroll
    for (int ct = 0; ct < 4; ++ct)
#pragma unroll
        for (int r = 0; r < 16; ++r) {
            const float sv = acc[ct][r];
            const float sa = sv - bv[ct];
            const float qd = fmaxf(sv - cv[ct], 1e-9f);
            gm[r] = fmaxf(gm[r], sa * __builtin_amdgcn_rcpf(qd));
        }
#pragma unroll
    for (int r = 0; r < 16; ++r)
#pragma unroll
        for (int off = 1; off < 32; off <<= 1)
            gm[r] = fmaxf(gm[r], __shfl_xor(gm[r], off));

    float* gmbuf = (float*)(lds + LDS_GM);
#pragma unroll
    for (int r = 0; r < 16; ++r) {
        const int row = (r & 3) + 8 * (r >> 2) + 4 * hi;
        if (li == 0) gmbuf[rg * 64 + row * 2 + cg] = gm[r];
    }
    __syncthreads();

    const float2 p2 = *(const float2*)(pivot + 2 * li);
    const int r0 = cg * 8;
#pragma unroll
    for (int rr = 0; rr < 8; ++rr) {
        const int r   = r0 + rr;
        const int row = (r & 3) + 8 * (r >> 2) + 4 * hi;
        const float g = fmaxf(gm[r], gmbuf[rg * 64 + row * 2 + (cg ^ 1)]);
        const int idx = base + (R0 + row) * DIMK + 2 * li;
        const float2 zz = *(const float2*)(z + idx);
        float2 o;
        o.x = fmaf(g, p2.x - zz.x, zz.x);
        o.y = fmaf(g, p2.y - zz.y, zz.y);
        *(float2*)(out + idx) = o;
    }
}

extern "C" void kernel_launch(void* const* d_in, const int* in_sizes, int n_in,
                              void* d_out, int out_size, void* d_ws, size_t ws_size,
                              hipStream_t stream) {
    const float* z     = (const float*)d_in[0];
    const float* pivot = (const float*)d_in[1];
    const float* At    = (const float*)d_in[2];
    const float* b     = (const float*)d_in[3];
    float* ws = (float*)d_ws;
    if (ws_size >= (size_t)WS_NEED) {
        // fast path: persistent 512-thr blocks, 4 waves/SIMD, At in LDS once
        precompute_at<<<dim3(1), dim3(MC), 0, stream>>>(pivot, At, ws);
        fused_constrain_p<<<dim3(PBLK), dim3(512), LDS_FP_SIZE, stream>>>(
            z, pivot, b, ws, (float*)d_out);
    } else {
        // safe path: 1 KB ws (cvec); per-block At split (round-3 proven)
        precompute_c<<<dim3(1), dim3(MC), 0, stream>>>(pivot, At, ws);
        fused_constrain_fb<<<dim3(NT), dim3(256), 0, stream>>>(
            z, pivot, At, b, ws, (float*)d_out);
    }
}